// Round 11
// baseline (5315.960 us; speedup 1.0000x reference)
//
#include <hip/hip_runtime.h>
#include <cstdint>

// ---------------------------------------------------------------------------
// Threefry-2x32 (JAX partitionable-mode compatible), host + device.
// ---------------------------------------------------------------------------
__host__ __device__ inline uint32_t tf_rotl32(uint32_t x, uint32_t r) {
  return (x << r) | (x >> (32u - r));
}

__host__ __device__ inline void threefry2x32(uint32_t k0, uint32_t k1,
                                             uint32_t x0, uint32_t x1,
                                             uint32_t* o0, uint32_t* o1) {
  uint32_t ks0 = k0, ks1 = k1, ks2 = k0 ^ k1 ^ 0x1BD11BDAu;
  x0 += ks0; x1 += ks1;
#define TF_R(r) { x0 += x1; x1 = tf_rotl32(x1, r); x1 ^= x0; }
  TF_R(13) TF_R(15) TF_R(26) TF_R(6)
  x0 += ks1; x1 += ks2 + 1u;
  TF_R(17) TF_R(29) TF_R(16) TF_R(24)
  x0 += ks2; x1 += ks0 + 2u;
  TF_R(13) TF_R(15) TF_R(26) TF_R(6)
  x0 += ks0; x1 += ks1 + 3u;
  TF_R(17) TF_R(29) TF_R(16) TF_R(24)
  x0 += ks1; x1 += ks2 + 4u;
  TF_R(13) TF_R(15) TF_R(26) TF_R(6)
  x0 += ks2; x1 += ks0 + 5u;
#undef TF_R
  *o0 = x0; *o1 = x1;
}

// ---------------------------------------------------------------------------
// Problem dims
// ---------------------------------------------------------------------------
#define BSZ   8192
#define KIN   784
#define HID   800
#define NOUT  10
#define NSTEP 25

// Verified R8: golden = JAX-on-CPU (XLA -> Eigen gebp). Eigen k-panels for
// K=784: [0,264) [264,528) [528,784), committed C += P_i; per-element
// sequential ascending-k chain within each panel. Since a in {0,1,2},
// rn(a*b) = a*b exactly, so fmaf == Eigen's mul-then-add bitwise.
// BK=16: 264 = tile16 kk8 (peel); 528 = tile-33 boundary (commit after t32).

// ---------------------------------------------------------------------------
// Kernel 1: Poisson encoding (JAX-faithful: truncated 2^-23 grid).
// enc = temp + 1 in {0,1,2}; sp = 0.5*enc (exact power-of-2 relation).
// ---------------------------------------------------------------------------
__global__ __launch_bounds__(256) void enc_kernel(const float* __restrict__ inp,
                                                  uint8_t* __restrict__ enc,
                                                  uint32_t k0, uint32_t k1) {
  int j = blockIdx.x * blockDim.x + threadIdx.x;
  if (j >= BSZ * KIN) return;
  uint32_t o0, o1;
  threefry2x32(k0, k1, 0u, (uint32_t)j, &o0, &o1);
  uint32_t bits = o0 ^ o1;
  float r = __uint_as_float((bits >> 9) | 0x3f800000u) - 1.0f;
  float x = inp[j];
  bool cond = (2.0f * r <= fabsf(x));
  int s = (x > 0.0f) ? 1 : ((x < 0.0f) ? -1 : 0);
  enc[j] = (uint8_t)(1 + (cond ? s : 0));
}

// ---------------------------------------------------------------------------
// Kernel 2 (fused): Eigen-panel GEMM + membrane update + spike, in-register.
// BM=128, BN=32, BK=16, 128 threads (2 waves), 8x4 acc/thread:
//   per kk: 3 ds_read_b128 per 32 fma (vs 2 per 16 in R10) -> VALU-bound.
// B staged with XOR-quad swizzle (stores ~spread, reads b128 conflict-free).
// ---------------------------------------------------------------------------
#define BM 128
#define BN 32
#define BK 16

__global__ __launch_bounds__(128) void gemm_kernel(const uint8_t* __restrict__ enc,
                                                   const float* __restrict__ w1,
                                                   float* __restrict__ mem1,
                                                   uint8_t* __restrict__ spk) {
  __shared__ float As[BK * BM];   // 8 KB, layout k*BM + m
  __shared__ float Bs[BK * BN];   // 2 KB, swizzled
  const int m0 = blockIdx.x * BM;
  const int n0 = blockIdx.y * BN;
  const int t  = threadIdx.x;      // 0..127
  const int tm = t >> 3;           // 0..15 -> 8 m-rows each
  const int tn = t & 7;            // 0..7  -> 4 n-cols each
  // A staging: thread t stages row t, all 16 k as one uint4 (16 u8).
  // Store bank = t%32 -> 2-way across a wave (free).
  // B staging: thread t stages row t>>2, float4 at k=(t&3)*4.
  const int brow = t >> 2;         // 0..31
  const int bk4  = (t & 3) * 4;

  float acc[8][4] = {};   // current panel chain
  float tot[8][4] = {};   // committed C

#define COMMIT()                                                   \
  {                                                                \
    _Pragma("unroll") for (int mi = 0; mi < 8; mi++)               \
      _Pragma("unroll") for (int ni = 0; ni < 4; ni++) {           \
        tot[mi][ni] = __fadd_rn(tot[mi][ni], acc[mi][ni]);         \
        acc[mi][ni] = 0.0f;                                        \
      }                                                            \
  }

#define MAC_RANGE(KB, KE)                                          \
  {                                                                \
    _Pragma("unroll") for (int kk = (KB); kk < (KE); kk++) {       \
      const int q = (kk >> 1) & 7;                                 \
      float a[8], b[4];                                            \
      *(float4*)&a[0] = *(const float4*)&As[kk * BM + (tm << 3)];  \
      *(float4*)&a[4] = *(const float4*)&As[kk * BM + (tm << 3) + 4]; \
      *(float4*)b = *(const float4*)&Bs[kk * BN + ((tn ^ q) << 2)]; \
      _Pragma("unroll") for (int mi = 0; mi < 8; mi++)             \
        _Pragma("unroll") for (int ni = 0; ni < 4; ni++)           \
          acc[mi][ni] = fmaf(a[mi], b[ni], acc[mi][ni]);           \
    }                                                              \
  }

  int k0 = 0;
  for (int tile = 0; tile < 49; tile++, k0 += BK) {
    // A tile: 128 rows x 16 k u8 -> f32. One uint4 per thread.
    {
      const uint8_t* src = enc + (size_t)(m0 + t) * KIN + k0;  // 16B aligned
      uint4 v = *(const uint4*)src;
      const uint32_t w[4] = {v.x, v.y, v.z, v.w};
#pragma unroll
      for (int c = 0; c < 4; c++) {
        As[(4 * c + 0) * BM + t] = (float)( w[c]        & 0xffu);
        As[(4 * c + 1) * BM + t] = (float)((w[c] >>  8) & 0xffu);
        As[(4 * c + 2) * BM + t] = (float)((w[c] >> 16) & 0xffu);
        As[(4 * c + 3) * BM + t] = (float)((w[c] >> 24)        );
      }
    }
    // B tile: 32 rows x 16 k f32, float4 per thread, swizzled store.
    {
      const float* src = w1 + (size_t)(n0 + brow) * KIN + k0 + bk4;
      float4 v = *(const float4*)src;
      const float f[4] = {v.x, v.y, v.z, v.w};
#pragma unroll
      for (int j = 0; j < 4; j++) {
        const int k = bk4 + j;
        const int q = (k >> 1) & 7;
        Bs[k * BN + (((brow >> 2) ^ q) << 2) + (brow & 3)] = f[j];
      }
    }
    __syncthreads();
    if (tile == 16) {            // k=256..271 contains panel boundary 264
      MAC_RANGE(0, 8)
      COMMIT()                   // tot = P0  (0 + P0 exact)
      MAC_RANGE(8, 16)
    } else {
      MAC_RANGE(0, 16)
    }
    __syncthreads();
    if (tile == 32) COMMIT()     // k=528 boundary: tot = P0 + P1
  }
  COMMIT()                       // tot = (P0+P1) + P2

  // ---- fused epilogue: g = 0.5*tot; membrane update; spike ----
#pragma unroll
  for (int mi = 0; mi < 8; mi++) {
    const size_t row = (size_t)(m0 + (tm << 3) + mi);
    float* mp = mem1 + row * HID + n0 + (tn << 2);
    float mold[4];
    *(float4*)mold = *(const float4*)mp;
    float mnew[4];
    uint32_t sbits = 0;
#pragma unroll
    for (int ni = 0; ni < 4; ni++) {
      float gv  = __fmul_rn(0.5f, tot[mi][ni]);                       // exact
      float m   = __fadd_rn(__fmul_rn(0.95f, mold[ni]), __fmul_rn(0.05f, gv));
      float thr = __fadd_rn(m, -1.0f);
      bool spike = thr > 0.0f;
      mnew[ni] = spike ? thr : m;        // reset m-1 == thr bitwise
      sbits |= (spike ? 1u : 0u) << (8 * ni);
    }
    *(float4*)mp = *(const float4*)mnew;
    *(uint32_t*)(spk + row * HID + n0 + (tn << 2)) = sbits;
  }
#undef MAC_RANGE
#undef COMMIT
}

// ---------------------------------------------------------------------------
// Kernel 3: spike x w2^T accumulation into mem2. One wave per batch row.
// mem2 never feeds back into spike decisions: order noise ~1e-7 << threshold.
// ---------------------------------------------------------------------------
__global__ __launch_bounds__(256) void spike_out_kernel(const uint8_t* __restrict__ spk,
                                                        const float* __restrict__ w2,
                                                        float* __restrict__ mem2) {
  __shared__ float w2s[NOUT * HID];   // 32 KB
  for (int i = threadIdx.x; i < NOUT * HID; i += 256) w2s[i] = w2[i];
  __syncthreads();

  const int wave = threadIdx.x / 64;
  const int lane = threadIdx.x % 64;
  const int b = blockIdx.x * 4 + wave;
  const uint8_t* srow = spk + (size_t)b * HID;

  float acc[NOUT];
#pragma unroll
  for (int i = 0; i < NOUT; i++) acc[i] = 0.0f;

  for (int j = lane; j < HID; j += 64) {
    if (srow[j]) {
#pragma unroll
      for (int i = 0; i < NOUT; i++) acc[i] += w2s[i * HID + j];
    }
  }
#pragma unroll
  for (int i = 0; i < NOUT; i++) {
    float v = acc[i];
    for (int off = 32; off > 0; off >>= 1) v += __shfl_down(v, off);
    if (lane == 0) mem2[(size_t)b * NOUT + i] += v;
  }
}

// ---------------------------------------------------------------------------
// Kernel 4: out = mem2 / num_steps
// ---------------------------------------------------------------------------
__global__ __launch_bounds__(256) void finalize_kernel(const float* __restrict__ mem2,
                                                       const int* __restrict__ ns,
                                                       float* __restrict__ out) {
  int i = blockIdx.x * blockDim.x + threadIdx.x;
  if (i < BSZ * NOUT) out[i] = mem2[i] / (float)(*ns);
}

// ---------------------------------------------------------------------------
extern "C" void kernel_launch(void* const* d_in, const int* in_sizes, int n_in,
                              void* d_out, int out_size, void* d_ws, size_t ws_size,
                              hipStream_t stream) {
  const float* inp = (const float*)d_in[0];
  const float* w1  = (const float*)d_in[1];
  const float* w2  = (const float*)d_in[2];
  const int*   dns = (const int*)d_in[3];
  float* out = (float*)d_out;

  char* ws = (char*)d_ws;
  size_t off = 0;
  uint8_t* enc = (uint8_t*)(ws + off);  off += (size_t)BSZ * KIN;          // 6.4 MB
  off = (off + 255) & ~(size_t)255;
  uint8_t* spk = (uint8_t*)(ws + off);  off += (size_t)BSZ * HID;          // 6.6 MB
  off = (off + 255) & ~(size_t)255;
  float* mem1 = (float*)(ws + off);     off += (size_t)BSZ * HID * 4;      // 26.2 MB
  float* mem2 = (float*)(ws + off);     off += (size_t)BSZ * NOUT * 4;     // 0.33 MB

  (void)hipMemsetAsync(mem1, 0, (size_t)BSZ * HID * 4, stream);
  (void)hipMemsetAsync(mem2, 0, (size_t)BSZ * NOUT * 4, stream);

  // Step keys: partitionable split — key_t = threefry((0,42), (0,t)).
  uint32_t keys[NSTEP][2];
  for (int t = 0; t < NSTEP; t++)
    threefry2x32(0u, 42u, 0u, (uint32_t)t, &keys[t][0], &keys[t][1]);

  const int n_elem = BSZ * KIN;
  for (int t = 0; t < NSTEP; t++) {
    enc_kernel<<<(n_elem + 255) / 256, 256, 0, stream>>>(inp, enc, keys[t][0], keys[t][1]);
    gemm_kernel<<<dim3(BSZ / BM, HID / BN), 128, 0, stream>>>(enc, w1, mem1, spk);
    spike_out_kernel<<<BSZ / 4, 256, 0, stream>>>(spk, w2, mem2);
  }
  finalize_kernel<<<(BSZ * NOUT + 255) / 256, 256, 0, stream>>>(mem2, dns, out);
}

// Round 12
// 5018.503 us; speedup vs baseline: 1.0593x; 1.0593x over previous
//
#include <hip/hip_runtime.h>
#include <cstdint>

// ---------------------------------------------------------------------------
// Threefry-2x32 (JAX partitionable-mode compatible), host + device.
// ---------------------------------------------------------------------------
__host__ __device__ inline uint32_t tf_rotl32(uint32_t x, uint32_t r) {
  return (x << r) | (x >> (32u - r));
}

__host__ __device__ inline void threefry2x32(uint32_t k0, uint32_t k1,
                                             uint32_t x0, uint32_t x1,
                                             uint32_t* o0, uint32_t* o1) {
  uint32_t ks0 = k0, ks1 = k1, ks2 = k0 ^ k1 ^ 0x1BD11BDAu;
  x0 += ks0; x1 += ks1;
#define TF_R(r) { x0 += x1; x1 = tf_rotl32(x1, r); x1 ^= x0; }
  TF_R(13) TF_R(15) TF_R(26) TF_R(6)
  x0 += ks1; x1 += ks2 + 1u;
  TF_R(17) TF_R(29) TF_R(16) TF_R(24)
  x0 += ks2; x1 += ks0 + 2u;
  TF_R(13) TF_R(15) TF_R(26) TF_R(6)
  x0 += ks0; x1 += ks1 + 3u;
  TF_R(17) TF_R(29) TF_R(16) TF_R(24)
  x0 += ks1; x1 += ks2 + 4u;
  TF_R(13) TF_R(15) TF_R(26) TF_R(6)
  x0 += ks2; x1 += ks0 + 5u;
#undef TF_R
  *o0 = x0; *o1 = x1;
}

// ---------------------------------------------------------------------------
// Problem dims
// ---------------------------------------------------------------------------
#define BSZ   8192
#define KIN   784
#define HID   800
#define NOUT  10
#define NSTEP 25

// Verified R8: golden = JAX-on-CPU (XLA -> Eigen gebp). Eigen k-panels for
// K=784: [0,264) [264,528) [528,784), committed C += P_i; per-element
// sequential ascending-k chain within each panel. Since a in {0,1,2},
// rn(a*b) = a*b exactly, so fmaf == Eigen's mul-then-add bitwise.
// BK=32: 264 = tile 8, kk 8 (peel); 528 = tile 16, kk 16 (peel);
// last tile (24) is half-width: MAC kk<16 only.

// ---------------------------------------------------------------------------
// Kernel 1: Poisson encoding (JAX-faithful: truncated 2^-23 grid).
// ---------------------------------------------------------------------------
__global__ __launch_bounds__(256) void enc_kernel(const float* __restrict__ inp,
                                                  uint8_t* __restrict__ enc,
                                                  uint32_t k0, uint32_t k1) {
  int j = blockIdx.x * blockDim.x + threadIdx.x;
  if (j >= BSZ * KIN) return;
  uint32_t o0, o1;
  threefry2x32(k0, k1, 0u, (uint32_t)j, &o0, &o1);
  uint32_t bits = o0 ^ o1;
  float r = __uint_as_float((bits >> 9) | 0x3f800000u) - 1.0f;
  float x = inp[j];
  bool cond = (2.0f * r <= fabsf(x));
  int s = (x > 0.0f) ? 1 : ((x < 0.0f) ? -1 : 0);
  enc[j] = (uint8_t)(1 + (cond ? s : 0));
}

// ---------------------------------------------------------------------------
// Kernel 2 (fused): Eigen-panel GEMM + membrane update + spike, in-register.
// BM=128, BN=32, BK=32, 256 threads, 4x4 acc/thread (R10's proven shape).
// Register prefetch: global loads for tile t+1 issued before MAC of tile t.
// B stored with XOR-quad swizzle (R11-validated: 0 conflicts).
// ---------------------------------------------------------------------------
#define BM 128
#define BN 32
#define BK 32
#define NTILE 25   // 24 full tiles + 1 half tile (k 768..783)

__global__ __launch_bounds__(256) void gemm_kernel(const uint8_t* __restrict__ enc,
                                                   const float* __restrict__ w1,
                                                   float* __restrict__ mem1,
                                                   uint8_t* __restrict__ spk) {
  __shared__ float As[BK * BM];   // 16 KB, layout k*BM + m
  __shared__ float Bs[BK * BN];   // 4 KB, swizzled
  const int m0 = blockIdx.x * BM;
  const int n0 = blockIdx.y * BN;
  const int t  = threadIdx.x;
  const int tn = t & 7;            // 4 n-cols each
  const int tm = t >> 3;           // 4 m-rows each
  // A staging: row t>>1 (0..127), 16 u8 at k-offset (t&1)*16 (one uint4).
  const int arow = t >> 1;
  const int ak   = (t & 1) * 16;
  // B staging: row t>>3 (0..31), float4 at k-offset (t&7)*4.
  const int brow = t >> 3;
  const int bk   = (t & 7) * 4;

  const uint8_t* aptr = enc + (size_t)(m0 + arow) * KIN;
  const float*   bptr = w1  + (size_t)(n0 + brow) * KIN;

  float acc[4][4] = {};   // current panel chain
  float tot[4][4] = {};   // committed C

  auto COMMIT = [&]() {
#pragma unroll
    for (int mi = 0; mi < 4; mi++)
#pragma unroll
      for (int ni = 0; ni < 4; ni++) {
        tot[mi][ni] = __fadd_rn(tot[mi][ni], acc[mi][ni]);
        acc[mi][ni] = 0.0f;
      }
  };

  auto MAC = [&](int KB, int KE) {
#pragma unroll 4
    for (int kk = KB; kk < KE; kk++) {
      const int q = (kk >> 1) & 7;
      float a[4], b[4];
      *(float4*)a = *(const float4*)&As[kk * BM + (tm << 2)];
      *(float4*)b = *(const float4*)&Bs[kk * BN + ((tn ^ q) << 2)];
#pragma unroll
      for (int mi = 0; mi < 4; mi++)
#pragma unroll
        for (int ni = 0; ni < 4; ni++)
          acc[mi][ni] = fmaf(a[mi], b[ni], acc[mi][ni]);
    }
  };

  // Prefetch tile 0.
  uint4  aval = *(const uint4*)(aptr + ak);
  float4 bval = *(const float4*)(bptr + bk);

  int k0 = 0;
  for (int tile = 0; tile < NTILE; tile++, k0 += BK) {
    // ---- stage current tile (guards only bite on the half tile 24) ----
    if (k0 + ak < KIN) {
      const uint32_t w[4] = {aval.x, aval.y, aval.z, aval.w};
#pragma unroll
      for (int c = 0; c < 4; c++) {
        As[(ak + 4 * c + 0) * BM + arow] = (float)( w[c]        & 0xffu);
        As[(ak + 4 * c + 1) * BM + arow] = (float)((w[c] >>  8) & 0xffu);
        As[(ak + 4 * c + 2) * BM + arow] = (float)((w[c] >> 16) & 0xffu);
        As[(ak + 4 * c + 3) * BM + arow] = (float)((w[c] >> 24)        );
      }
    }
    if (k0 + bk < KIN) {
      const float f[4] = {bval.x, bval.y, bval.z, bval.w};
#pragma unroll
      for (int j = 0; j < 4; j++) {
        const int k = bk + j;
        const int q = (k >> 1) & 7;
        Bs[k * BN + ((((brow >> 2) ^ q) << 2) | (brow & 3))] = f[j];
      }
    }
    __syncthreads();
    // ---- prefetch next tile (overlaps with MAC below) ----
    if (tile + 1 < NTILE) {
      const int kn = k0 + BK;
      const int ka = (kn + ak + 16 <= KIN) ? (kn + ak) : kn;   // clamp, unused
      const int kb = (kn + bk + 4  <= KIN) ? (kn + bk) : kn;   // clamp, unused
      aval = *(const uint4*)(aptr + ka);
      bval = *(const float4*)(bptr + kb);
    }
    // ---- MAC with Eigen panel commits ----
    if (tile == 8)       { MAC(0, 8);  COMMIT(); MAC(8, 32); }   // k=264
    else if (tile == 16) { MAC(0, 16); COMMIT(); MAC(16, 32); }  // k=528
    else if (tile == 24) { MAC(0, 16); }                         // half tile
    else                 { MAC(0, 32); }
    __syncthreads();
  }
  COMMIT();   // tot = (P0+P1) + P2

  // ---- fused epilogue: g = 0.5*tot; membrane update; spike ----
#pragma unroll
  for (int mi = 0; mi < 4; mi++) {
    const size_t row = (size_t)(m0 + (tm << 2) + mi);
    float* mp = mem1 + row * HID + n0 + (tn << 2);
    float mold[4];
    *(float4*)mold = *(const float4*)mp;
    float mnew[4];
    uint32_t sbits = 0;
#pragma unroll
    for (int ni = 0; ni < 4; ni++) {
      float gv  = __fmul_rn(0.5f, tot[mi][ni]);                       // exact
      float m   = __fadd_rn(__fmul_rn(0.95f, mold[ni]), __fmul_rn(0.05f, gv));
      float thr = __fadd_rn(m, -1.0f);
      bool spike = thr > 0.0f;
      mnew[ni] = spike ? thr : m;        // reset m-1 == thr bitwise
      sbits |= (spike ? 1u : 0u) << (8 * ni);
    }
    *(float4*)mp = *(const float4*)mnew;
    *(uint32_t*)(spk + row * HID + n0 + (tn << 2)) = sbits;
  }
}

// ---------------------------------------------------------------------------
// Kernel 3: spike x w2^T accumulation into mem2. One wave per batch row.
// mem2 never feeds back into spike decisions: order noise ~1e-7 << threshold.
// ---------------------------------------------------------------------------
__global__ __launch_bounds__(256) void spike_out_kernel(const uint8_t* __restrict__ spk,
                                                        const float* __restrict__ w2,
                                                        float* __restrict__ mem2) {
  __shared__ float w2s[NOUT * HID];   // 32 KB
  for (int i = threadIdx.x; i < NOUT * HID; i += 256) w2s[i] = w2[i];
  __syncthreads();

  const int wave = threadIdx.x / 64;
  const int lane = threadIdx.x % 64;
  const int b = blockIdx.x * 4 + wave;
  const uint8_t* srow = spk + (size_t)b * HID;

  float acc[NOUT];
#pragma unroll
  for (int i = 0; i < NOUT; i++) acc[i] = 0.0f;

  for (int j = lane; j < HID; j += 64) {
    if (srow[j]) {
#pragma unroll
      for (int i = 0; i < NOUT; i++) acc[i] += w2s[i * HID + j];
    }
  }
#pragma unroll
  for (int i = 0; i < NOUT; i++) {
    float v = acc[i];
    for (int off = 32; off > 0; off >>= 1) v += __shfl_down(v, off);
    if (lane == 0) mem2[(size_t)b * NOUT + i] += v;
  }
}

// ---------------------------------------------------------------------------
// Kernel 4: out = mem2 / num_steps
// ---------------------------------------------------------------------------
__global__ __launch_bounds__(256) void finalize_kernel(const float* __restrict__ mem2,
                                                       const int* __restrict__ ns,
                                                       float* __restrict__ out) {
  int i = blockIdx.x * blockDim.x + threadIdx.x;
  if (i < BSZ * NOUT) out[i] = mem2[i] / (float)(*ns);
}

// ---------------------------------------------------------------------------
extern "C" void kernel_launch(void* const* d_in, const int* in_sizes, int n_in,
                              void* d_out, int out_size, void* d_ws, size_t ws_size,
                              hipStream_t stream) {
  const float* inp = (const float*)d_in[0];
  const float* w1  = (const float*)d_in[1];
  const float* w2  = (const float*)d_in[2];
  const int*   dns = (const int*)d_in[3];
  float* out = (float*)d_out;

  char* ws = (char*)d_ws;
  size_t off = 0;
  uint8_t* enc = (uint8_t*)(ws + off);  off += (size_t)BSZ * KIN;          // 6.4 MB
  off = (off + 255) & ~(size_t)255;
  uint8_t* spk = (uint8_t*)(ws + off);  off += (size_t)BSZ * HID;          // 6.6 MB
  off = (off + 255) & ~(size_t)255;
  float* mem1 = (float*)(ws + off);     off += (size_t)BSZ * HID * 4;      // 26.2 MB
  float* mem2 = (float*)(ws + off);     off += (size_t)BSZ * NOUT * 4;     // 0.33 MB

  (void)hipMemsetAsync(mem1, 0, (size_t)BSZ * HID * 4, stream);
  (void)hipMemsetAsync(mem2, 0, (size_t)BSZ * NOUT * 4, stream);

  // Step keys: partitionable split — key_t = threefry((0,42), (0,t)).
  uint32_t keys[NSTEP][2];
  for (int t = 0; t < NSTEP; t++)
    threefry2x32(0u, 42u, 0u, (uint32_t)t, &keys[t][0], &keys[t][1]);

  const int n_elem = BSZ * KIN;
  for (int t = 0; t < NSTEP; t++) {
    enc_kernel<<<(n_elem + 255) / 256, 256, 0, stream>>>(inp, enc, keys[t][0], keys[t][1]);
    gemm_kernel<<<dim3(BSZ / BM, HID / BN), 256, 0, stream>>>(enc, w1, mem1, spk);
    spike_out_kernel<<<BSZ / 4, 256, 0, stream>>>(spk, w2, mem2);
  }
  finalize_kernel<<<(BSZ * NOUT + 255) / 256, 256, 0, stream>>>(mem2, dns, out);
}

// Round 13
// 4906.017 us; speedup vs baseline: 1.0836x; 1.0229x over previous
//
#include <hip/hip_runtime.h>
#include <cstdint>

// ---------------------------------------------------------------------------
// Threefry-2x32 (JAX partitionable-mode compatible), host + device.
// ---------------------------------------------------------------------------
__host__ __device__ inline uint32_t tf_rotl32(uint32_t x, uint32_t r) {
  return (x << r) | (x >> (32u - r));
}

__host__ __device__ inline void threefry2x32(uint32_t k0, uint32_t k1,
                                             uint32_t x0, uint32_t x1,
                                             uint32_t* o0, uint32_t* o1) {
  uint32_t ks0 = k0, ks1 = k1, ks2 = k0 ^ k1 ^ 0x1BD11BDAu;
  x0 += ks0; x1 += ks1;
#define TF_R(r) { x0 += x1; x1 = tf_rotl32(x1, r); x1 ^= x0; }
  TF_R(13) TF_R(15) TF_R(26) TF_R(6)
  x0 += ks1; x1 += ks2 + 1u;
  TF_R(17) TF_R(29) TF_R(16) TF_R(24)
  x0 += ks2; x1 += ks0 + 2u;
  TF_R(13) TF_R(15) TF_R(26) TF_R(6)
  x0 += ks0; x1 += ks1 + 3u;
  TF_R(17) TF_R(29) TF_R(16) TF_R(24)
  x0 += ks1; x1 += ks2 + 4u;
  TF_R(13) TF_R(15) TF_R(26) TF_R(6)
  x0 += ks2; x1 += ks0 + 5u;
#undef TF_R
  *o0 = x0; *o1 = x1;
}

// ---------------------------------------------------------------------------
// Problem dims
// ---------------------------------------------------------------------------
#define BSZ   8192
#define KIN   784
#define HID   800
#define NOUT  10
#define NSTEP 25

// Verified R8: golden = JAX-on-CPU (XLA -> Eigen gebp). Eigen k-panels for
// K=784: [0,264) [264,528) [528,784), committed C += P_i; per-element
// sequential ascending-k chain within each panel. Since a in {0,1,2},
// rn(a*b) = a*b exactly, so fmaf == Eigen's mul-then-add bitwise.
// BK=16: 264 = tile 16, kk 8 (peel); 528 = after tile 32 (49 tiles, no tail).

// ---------------------------------------------------------------------------
// Kernel 1: Poisson encoding (JAX-faithful: truncated 2^-23 grid).
// ---------------------------------------------------------------------------
__global__ __launch_bounds__(256) void enc_kernel(const float* __restrict__ inp,
                                                  uint8_t* __restrict__ enc,
                                                  uint32_t k0, uint32_t k1) {
  int j = blockIdx.x * blockDim.x + threadIdx.x;
  if (j >= BSZ * KIN) return;
  uint32_t o0, o1;
  threefry2x32(k0, k1, 0u, (uint32_t)j, &o0, &o1);
  uint32_t bits = o0 ^ o1;
  float r = __uint_as_float((bits >> 9) | 0x3f800000u) - 1.0f;
  float x = inp[j];
  bool cond = (2.0f * r <= fabsf(x));
  int s = (x > 0.0f) ? 1 : ((x < 0.0f) ? -1 : 0);
  enc[j] = (uint8_t)(1 + (cond ? s : 0));
}

// ---------------------------------------------------------------------------
// Kernel 2 (fused): Eigen-panel GEMM + membrane update + spike, in-register.
// R10 skeleton (BM=128, BN=32, BK=16, 256 thr, 4x4 acc) + ping-pong LDS:
// one barrier per tile; global prefetch of t+1 issued before MAC of t;
// staging stores go to the idle buffer half.
// ---------------------------------------------------------------------------
#define BM 128
#define BN 32
#define BK 16
#define NTILE 49   // 49*16 = 784 exactly

__global__ __launch_bounds__(256) void gemm_kernel(const uint8_t* __restrict__ enc,
                                                   const float* __restrict__ w1,
                                                   float* __restrict__ mem1,
                                                   uint8_t* __restrict__ spk) {
  __shared__ float As[2][BK * BM];   // 2 x 8 KB, layout k*BM + m
  __shared__ float Bs[2][BK * BN];   // 2 x 2 KB, swizzled
  const int m0 = blockIdx.x * BM;
  const int n0 = blockIdx.y * BN;
  const int t  = threadIdx.x;
  const int tn = t & 7;            // 4 n-cols each
  const int tm = t >> 3;           // 4 m-rows each
  // A staging (R10): row t>>1 (0..127), 8 u8 at k-offset (t&1)*8 (uint2).
  const int arow  = t >> 1;
  const int akofs = (t & 1) * 8;
  // B staging (R10): row t>>3 (0..31), float2 at k=(t&7)*2, XOR-quad swizzle.
  const int brow  = t >> 3;
  const int bkofs = (t & 7) * 2;
  const int bswz  = (((brow >> 2) ^ (t & 7)) << 2) + (brow & 3);

  const uint8_t* aptr = enc + (size_t)(m0 + arow) * KIN + akofs;
  const float*   bptr = w1  + (size_t)(n0 + brow) * KIN + bkofs;

  float acc[4][4] = {};   // current panel chain
  float tot[4][4] = {};   // committed C

#define COMMIT()                                                   \
  {                                                                \
    _Pragma("unroll") for (int mi = 0; mi < 4; mi++)               \
      _Pragma("unroll") for (int ni = 0; ni < 4; ni++) {           \
        tot[mi][ni] = __fadd_rn(tot[mi][ni], acc[mi][ni]);         \
        acc[mi][ni] = 0.0f;                                        \
      }                                                            \
  }

#define MAC_RANGE(P, KB, KE)                                       \
  {                                                                \
    _Pragma("unroll") for (int kk = (KB); kk < (KE); kk++) {       \
      const int q = (kk >> 1) & 7;                                 \
      float a[4], b[4];                                            \
      *(float4*)a = *(const float4*)&As[P][kk * BM + (tm << 2)];   \
      *(float4*)b = *(const float4*)&Bs[P][kk * BN + ((tn ^ q) << 2)]; \
      _Pragma("unroll") for (int mi = 0; mi < 4; mi++)             \
        _Pragma("unroll") for (int ni = 0; ni < 4; ni++)           \
          acc[mi][ni] = fmaf(a[mi], b[ni], acc[mi][ni]);           \
    }                                                              \
  }

#define STAGE(P, AV, BV)                                           \
  {                                                                \
    As[P][(akofs + 0) * BM + arow] = (float)( (AV).x        & 0xffu); \
    As[P][(akofs + 1) * BM + arow] = (float)(((AV).x >>  8) & 0xffu); \
    As[P][(akofs + 2) * BM + arow] = (float)(((AV).x >> 16) & 0xffu); \
    As[P][(akofs + 3) * BM + arow] = (float)(((AV).x >> 24)        ); \
    As[P][(akofs + 4) * BM + arow] = (float)( (AV).y        & 0xffu); \
    As[P][(akofs + 5) * BM + arow] = (float)(((AV).y >>  8) & 0xffu); \
    As[P][(akofs + 6) * BM + arow] = (float)(((AV).y >> 16) & 0xffu); \
    As[P][(akofs + 7) * BM + arow] = (float)(((AV).y >> 24)        ); \
    Bs[P][(bkofs + 0) * BN + bswz] = (BV).x;                          \
    Bs[P][(bkofs + 1) * BN + bswz] = (BV).y;                          \
  }

  // Stage tile 0 into buffer 0.
  {
    uint2  av = *(const uint2*)(aptr);
    float2 bv = *(const float2*)(bptr);
    STAGE(0, av, bv)
  }
  __syncthreads();

  uint2  avn;
  float2 bvn;
  for (int tile = 0; tile < NTILE; tile++) {
    const int p = tile & 1;
    // Prefetch next tile into registers (issues loads; latency hidden by MAC).
    if (tile + 1 < NTILE) {
      avn = *(const uint2*)(aptr + (tile + 1) * BK);
      bvn = *(const float2*)(bptr + (tile + 1) * BK);
    }
    // MAC current tile with Eigen panel commits.
    if (tile == 16) { MAC_RANGE(p, 0, 8) COMMIT() MAC_RANGE(p, 8, 16) }  // k=264
    else            { MAC_RANGE(p, 0, 16) }
    if (tile == 32) COMMIT()                                             // k=528
    // Stage next tile into the idle half, then one barrier.
    if (tile + 1 < NTILE) {
      STAGE(1 - p, avn, bvn)
      __syncthreads();
    }
  }
  COMMIT()   // tot = (P0+P1) + P2

  // ---- fused epilogue: g = 0.5*tot; membrane update; spike ----
#pragma unroll
  for (int mi = 0; mi < 4; mi++) {
    const size_t row = (size_t)(m0 + (tm << 2) + mi);
    float* mp = mem1 + row * HID + n0 + (tn << 2);
    float mold[4];
    *(float4*)mold = *(const float4*)mp;
    float mnew[4];
    uint32_t sbits = 0;
#pragma unroll
    for (int ni = 0; ni < 4; ni++) {
      float gv  = __fmul_rn(0.5f, tot[mi][ni]);                       // exact
      float m   = __fadd_rn(__fmul_rn(0.95f, mold[ni]), __fmul_rn(0.05f, gv));
      float thr = __fadd_rn(m, -1.0f);
      bool spike = thr > 0.0f;
      mnew[ni] = spike ? thr : m;        // reset m-1 == thr bitwise
      sbits |= (spike ? 1u : 0u) << (8 * ni);
    }
    *(float4*)mp = *(const float4*)mnew;
    *(uint32_t*)(spk + row * HID + n0 + (tn << 2)) = sbits;
  }
#undef MAC_RANGE
#undef COMMIT
#undef STAGE
}

// ---------------------------------------------------------------------------
// Kernel 3: spike x w2^T accumulation into mem2. One wave per batch row.
// mem2 never feeds back into spike decisions: order noise ~1e-7 << threshold.
// ---------------------------------------------------------------------------
__global__ __launch_bounds__(256) void spike_out_kernel(const uint8_t* __restrict__ spk,
                                                        const float* __restrict__ w2,
                                                        float* __restrict__ mem2) {
  __shared__ float w2s[NOUT * HID];   // 32 KB
  for (int i = threadIdx.x; i < NOUT * HID; i += 256) w2s[i] = w2[i];
  __syncthreads();

  const int wave = threadIdx.x / 64;
  const int lane = threadIdx.x % 64;
  const int b = blockIdx.x * 4 + wave;
  const uint8_t* srow = spk + (size_t)b * HID;

  float acc[NOUT];
#pragma unroll
  for (int i = 0; i < NOUT; i++) acc[i] = 0.0f;

  for (int j = lane; j < HID; j += 64) {
    if (srow[j]) {
#pragma unroll
      for (int i = 0; i < NOUT; i++) acc[i] += w2s[i * HID + j];
    }
  }
#pragma unroll
  for (int i = 0; i < NOUT; i++) {
    float v = acc[i];
    for (int off = 32; off > 0; off >>= 1) v += __shfl_down(v, off);
    if (lane == 0) mem2[(size_t)b * NOUT + i] += v;
  }
}

// ---------------------------------------------------------------------------
// Kernel 4: out = mem2 / num_steps
// ---------------------------------------------------------------------------
__global__ __launch_bounds__(256) void finalize_kernel(const float* __restrict__ mem2,
                                                       const int* __restrict__ ns,
                                                       float* __restrict__ out) {
  int i = blockIdx.x * blockDim.x + threadIdx.x;
  if (i < BSZ * NOUT) out[i] = mem2[i] / (float)(*ns);
}

// ---------------------------------------------------------------------------
extern "C" void kernel_launch(void* const* d_in, const int* in_sizes, int n_in,
                              void* d_out, int out_size, void* d_ws, size_t ws_size,
                              hipStream_t stream) {
  const float* inp = (const float*)d_in[0];
  const float* w1  = (const float*)d_in[1];
  const float* w2  = (const float*)d_in[2];
  const int*   dns = (const int*)d_in[3];
  float* out = (float*)d_out;

  char* ws = (char*)d_ws;
  size_t off = 0;
  uint8_t* enc = (uint8_t*)(ws + off);  off += (size_t)BSZ * KIN;          // 6.4 MB
  off = (off + 255) & ~(size_t)255;
  uint8_t* spk = (uint8_t*)(ws + off);  off += (size_t)BSZ * HID;          // 6.6 MB
  off = (off + 255) & ~(size_t)255;
  float* mem1 = (float*)(ws + off);     off += (size_t)BSZ * HID * 4;      // 26.2 MB
  float* mem2 = (float*)(ws + off);     off += (size_t)BSZ * NOUT * 4;     // 0.33 MB

  (void)hipMemsetAsync(mem1, 0, (size_t)BSZ * HID * 4, stream);
  (void)hipMemsetAsync(mem2, 0, (size_t)BSZ * NOUT * 4, stream);

  // Step keys: partitionable split — key_t = threefry((0,42), (0,t)).
  uint32_t keys[NSTEP][2];
  for (int t = 0; t < NSTEP; t++)
    threefry2x32(0u, 42u, 0u, (uint32_t)t, &keys[t][0], &keys[t][1]);

  const int n_elem = BSZ * KIN;
  for (int t = 0; t < NSTEP; t++) {
    enc_kernel<<<(n_elem + 255) / 256, 256, 0, stream>>>(inp, enc, keys[t][0], keys[t][1]);
    gemm_kernel<<<dim3(BSZ / BM, HID / BN), 256, 0, stream>>>(enc, w1, mem1, spk);
    spike_out_kernel<<<BSZ / 4, 256, 0, stream>>>(spk, w2, mem2);
  }
  finalize_kernel<<<(BSZ * NOUT + 255) / 256, 256, 0, stream>>>(mem2, dns, out);
}